// Round 8
// baseline (25931.116 us; speedup 1.0000x reference)
//
#include <hip/hip_runtime.h>

// 2-layer LSTM (B=64, T=2048, H=256), persistent kernel, SINGLE-XCD edition.
// R13 = R7 (verified 5927us) minus serial overhead, using ONLY mechanisms
// proven in passing rounds (R5/R6/R7/R10):
//  (1) ONE barrier per phase (was 2): LDS gate tiles double-buffered by
//      parity; per-WAVE stamps (own vmcnt(0) drain + lane0 stamp) and
//      per-WAVE polling (all 256 wave-flags, agent atomic loads). Wave skew
//      is bounded at 1 phase by the poll, so the single __syncthreads per
//      phase aligns across waves; parity indexing keeps stragglers safe.
//  (2) FC h1 agent load ISSUED before the poll, CONSUMED after it (hides
//      the agent RT under the poll spin).
//  (3) stamps are atomicExch (device-scope RMW -> lands at TCC, freshest
//      possible for the agent-load observers; R5 proved RMW freshness).
// NOT used: hand-rolled sc0 loads in any spin loop (R11/R12 hung 2-for-2 on
// that pattern; sc0 asm loads remain ONLY on the streaming A-frag path,
// where R6/R7 proved them over thousands of phases).
// Flag semantics unchanged from R7: stamp p+2 = "finished phase p (reads
// drained before stamp)"; poll ALL flags >= p+2 before entering p+1.
// WAR on parity-2 h slots gated by the poll exactly as in R7.

#define NWG 64      // participant workgroups
#define NSTRIP 32   // h strips (8 dims each)
#define BB 64
#define TT 2048
#define HH 256
#define HS 8        // dims per strip
#define HSW 4       // hidden dims per WG per layer
#define RS 16       // gate rows per WG per layer (4*HSW)
#define NFLAG 256   // 64 WGs x 4 waves
#define FSTR 8      // flag stride in dwords (32B -> <=4 RMWs per 128B line)

// workspace layout (dwords)
#define WS_H0    0        // 16384 dwords
#define WS_H1    16384    // 16384 dwords
#define WS_FLAGS 32768    // 256 flags, stride 8 dwords (2048 dwords)
#define WS_CNT   34816    // 16 dwords
#define WS_WIN   34832    // 1 dword
#define WS_NZERO 34832    // zeroed [0, WS_NZERO); winner set separately

typedef float  f32x4  __attribute__((ext_vector_type(4)));
typedef __bf16 bf16x8 __attribute__((ext_vector_type(8)));
typedef unsigned long long u64;
typedef unsigned int u32;

__device__ __forceinline__ float sigf(float x)   { return 1.0f / (1.0f + __expf(-x)); }
__device__ __forceinline__ float tanh_f(float x) { return 2.0f / (1.0f + __expf(-2.0f * x)) - 1.0f; }

__global__ void init_ws(u32* ws) {
  int i = blockIdx.x * blockDim.x + threadIdx.x;
  for (; i < WS_NZERO; i += gridDim.x * blockDim.x) ws[i] = 0u;
  if (blockIdx.x == 0 && threadIdx.x == 0) ((int*)ws)[WS_WIN] = -1;
}

__global__ __launch_bounds__(256, 2) void lstm2_persistent(
    const float* __restrict__ y,
    const float* __restrict__ Wih0, const float* __restrict__ Whh0,
    const float* __restrict__ bih0, const float* __restrict__ bhh0,
    const float* __restrict__ Wih1, const float* __restrict__ Whh1,
    const float* __restrict__ bih1, const float* __restrict__ bhh1,
    const float* __restrict__ Wfc,  const float* __restrict__ bfc,
    float* __restrict__ out,
    u32* __restrict__ ws)
{
  __bf16* h0buf = (__bf16*)(ws + WS_H0);   // [2][NSTRIP][BB][HS]
  __bf16* h1buf = (__bf16*)(ws + WS_H1);   // [2][NSTRIP][BB][HS]
  int*    flags = (int*)(ws + WS_FLAGS);   // flag f at flags[f*FSTR]
  int*    cnt   = (int*)(ws + WS_CNT);
  int*    winner= (int*)(ws + WS_WIN);

  const int tid  = threadIdx.x;

  // ---- same-XCD election: first 64 WGs on one XCD participate, rest exit ----
  __shared__ int s_w;
  if (tid == 0) {
    // HW_REG_XCC_ID = 20, offset 0, size 32 -> imm = 20 | (31<<11)
    int xcc = __builtin_amdgcn_s_getreg(20 | (31 << 11)) & 0xF;
    int r = atomicAdd(&cnt[xcc], 1);               // device-scope (IC), one-time
    if (r == NWG - 1) atomicCAS(winner, -1, xcc);  // 64th registrant claims
    int wv;
    while ((wv = __hip_atomic_load(winner, __ATOMIC_RELAXED,
                                   __HIP_MEMORY_SCOPE_AGENT)) == -1) {}
    s_w = (wv == xcc && r < NWG) ? r : -1;
  }
  __syncthreads();
  const int w = s_w;
  if (w < 0) return;   // non-participant WG exits, frees its CU

  const int wave = tid >> 6;
  const int lane = tid & 63;
  const int ml   = lane & 15;   // row-within-tile for A, gate row for B
  const int kq   = lane >> 4;   // k-quad

  // double-buffered gate tiles (by phase parity) -> stragglers of phase p
  // and leaders of phase p+1 never touch the same buffer.
  __shared__ float lds_g0[2][RS][BB + 4];
  __shared__ float lds_g1[2][RS][BB + 4];
  __shared__ float s_wih0[RS][4];
  __shared__ float s_b0[RS];
  __shared__ float s_b1[RS];

  // ---- load recurrent weights into per-wave VGPR B-fragments (bf16) ----
  // local gate row r = ml (0..15): gate = r>>2, dim-in-WG = r&3
  bf16x8 w0f[8];    // layer0: K=256
  bf16x8 w1f[16];   // layer1: K=512 = [Wih1 | Whh1]
  {
    const int r     = ml;
    const int rglob = (r >> 2) * 256 + w * HSW + (r & 3);
    #pragma unroll
    for (int s = 0; s < 8; s++) {
      const float* src = Whh0 + rglob * HH + s * 32 + kq * 8;
      bf16x8 f;
      #pragma unroll
      for (int j = 0; j < 8; j++) f[j] = (__bf16)src[j];
      w0f[s] = f;
    }
    #pragma unroll
    for (int s = 0; s < 16; s++) {
      const int k = s * 32 + kq * 8;
      const float* src = (k < 256) ? (Wih1 + rglob * HH + k)
                                   : (Whh1 + rglob * HH + (k - 256));
      bf16x8 f;
      #pragma unroll
      for (int j = 0; j < 8; j++) f[j] = (__bf16)src[j];
      w1f[s] = f;
    }
  }

  // ---- epilogue tables in LDS ----
  if (tid < RS) {
    const int r     = tid;
    const int rglob = (r >> 2) * 256 + w * HSW + (r & 3);
    s_b0[r] = bih0[rglob] + bhh0[rglob];
    s_b1[r] = bih1[rglob] + bhh1[rglob];
    #pragma unroll
    for (int j = 0; j < 4; j++) s_wih0[r][j] = Wih0[rglob * 4 + j];
  }
  __syncthreads();

  float c0 = 0.f, c1 = 0.f;

  const int b_epi = tid >> 2;          // epilogue batch (1 dim per thread)
  const int dl    = tid & 3;           // hidden dim within WG

  // FC constants (waves 0,1 only use them)
  const float wfc0 = Wfc[wave < 2 ? (wave * HH + lane * 4 + 0) : 0];
  const float wfc1 = Wfc[wave < 2 ? (wave * HH + lane * 4 + 1) : 0];
  const float wfc2 = Wfc[wave < 2 ? (wave * HH + lane * 4 + 2) : 0];
  const float wfc3 = Wfc[wave < 2 ? (wave * HH + lane * 4 + 3) : 0];

  // sliding 4-tap input window: x[j] holds y[b_epi, p-3+j] (or -100 pad)
  float x[4] = {-100.0f, -100.0f, -100.0f, -100.0f};

  for (int p = 0; p < TT + 2; p++) {
    const int par  = p & 1;       // parity written by L0 this phase
    const int parm = par ^ 1;     // parity of h0(p-1) / h1(p-1)

    const bool doL0 = (p < TT);
    const bool doL1 = (p >= 1 && p <= TT);

    // ---- A-fragments: h0(p-1) and h1(p-2), L1-bypassing sc0 loads ----
    // (streaming one-shot loads: the PROVEN sc0 use; never spun on)
    bf16x8 a0[8], a1[8];
    {
      const int row = wave * 16 + ml;
      const __bf16* h0p = h0buf + (parm * NSTRIP * BB + kq * BB + row) * HS;
      const __bf16* h1p = h1buf + (par  * NSTRIP * BB + kq * BB + row) * HS;
      #pragma unroll
      for (int s = 0; s < 8; s++)
        asm volatile("global_load_dwordx4 %0, %1, off sc0"
                     : "=v"(a0[s]) : "v"(h0p + s * 4 * BB * HS) : "memory");
      #pragma unroll
      for (int s = 0; s < 8; s++)
        asm volatile("global_load_dwordx4 %0, %1, off sc0"
                     : "=v"(a1[s]) : "v"(h1p + s * 4 * BB * HS) : "memory");
    }

    // ---- slide the input window (overlaps the sc0 load latency) ----
    x[0] = x[1]; x[1] = x[2]; x[2] = x[3];
    x[3] = (p < TT) ? y[b_epi * TT + p] : -100.0f;

    // drain the sc0 loads; fence so MFMAs can't hoist above the wait (rule 18)
    asm volatile("s_waitcnt vmcnt(0)" ::: "memory");
    __builtin_amdgcn_sched_barrier(0);

    f32x4 acc0  = {0.f,0.f,0.f,0.f};
    f32x4 acc1a = {0.f,0.f,0.f,0.f};
    f32x4 acc1b = {0.f,0.f,0.f,0.f};

    if (doL0) {
      #pragma unroll
      for (int s = 0; s < 8; s++)
        acc0 = __builtin_amdgcn_mfma_f32_16x16x32_bf16(a0[s], w0f[s], acc0, 0, 0, 0);
    }
    if (doL1) {
      #pragma unroll
      for (int s = 0; s < 8; s++)
        acc1a = __builtin_amdgcn_mfma_f32_16x16x32_bf16(a0[s], w1f[s], acc1a, 0, 0, 0);
      #pragma unroll
      for (int s = 0; s < 8; s++)
        acc1b = __builtin_amdgcn_mfma_f32_16x16x32_bf16(a1[s], w1f[s + 8], acc1b, 0, 0, 0);
    }

    // ---- spill gates to parity buffer ----
    {
      const int bb = wave * 16 + kq * 4;
      if (doL0) {
        #pragma unroll
        for (int j = 0; j < 4; j++) lds_g0[par][ml][bb + j] = acc0[j];
      }
      if (doL1) {
        #pragma unroll
        for (int j = 0; j < 4; j++) lds_g1[par][ml][bb + j] = acc1a[j] + acc1b[j];
      }
    }
    __syncthreads();   // the ONE barrier per phase

    // ---- L0 epilogue: gates -> (c0,h0), publish h0(p) ----
    if (doL0) {
      const float gi = lds_g0[par][dl     ][b_epi] + s_b0[dl     ]
        + s_wih0[dl     ][0]*x[0] + s_wih0[dl     ][1]*x[1] + s_wih0[dl     ][2]*x[2] + s_wih0[dl     ][3]*x[3];
      const float gf = lds_g0[par][4 + dl ][b_epi] + s_b0[4 + dl ]
        + s_wih0[4 + dl ][0]*x[0] + s_wih0[4 + dl ][1]*x[1] + s_wih0[4 + dl ][2]*x[2] + s_wih0[4 + dl ][3]*x[3];
      const float gg = lds_g0[par][8 + dl ][b_epi] + s_b0[8 + dl ]
        + s_wih0[8 + dl ][0]*x[0] + s_wih0[8 + dl ][1]*x[1] + s_wih0[8 + dl ][2]*x[2] + s_wih0[8 + dl ][3]*x[3];
      const float go = lds_g0[par][12 + dl][b_epi] + s_b0[12 + dl]
        + s_wih0[12 + dl][0]*x[0] + s_wih0[12 + dl][1]*x[1] + s_wih0[12 + dl][2]*x[2] + s_wih0[12 + dl][3]*x[3];
      const float cn = sigf(gf) * c0 + sigf(gi) * tanh_f(gg);
      c0 = cn;
      const float hn = sigf(go) * tanh_f(cn);
      h0buf[(par * NSTRIP * BB + (w >> 1) * BB + b_epi) * HS + (w & 1) * 4 + dl] = (__bf16)hn;
    }

    // ---- L1 epilogue: publish h1(p-1) ----
    if (doL1) {
      const float gi = lds_g1[par][dl     ][b_epi] + s_b1[dl     ];
      const float gf = lds_g1[par][4 + dl ][b_epi] + s_b1[4 + dl ];
      const float gg = lds_g1[par][8 + dl ][b_epi] + s_b1[8 + dl ];
      const float go = lds_g1[par][12 + dl][b_epi] + s_b1[12 + dl];
      const float cn = sigf(gf) * c1 + sigf(gi) * tanh_f(gg);
      c1 = cn;
      const float hn = sigf(go) * tanh_f(cn);
      h1buf[(parm * NSTRIP * BB + (w >> 1) * BB + b_epi) * HS + (w & 1) * 4 + dl] = (__bf16)hn;
    }

    // ---- per-wave stamp: drain OWN stores, RMW stamp own flag ----
    asm volatile("s_waitcnt vmcnt(0)" ::: "memory");
    if (lane == 0)
      atomicExch(&flags[(w * 4 + wave) * FSTR], p + 2);   // device-scope RMW

    // ---- FC load issued now (agent path), consumed after the poll ----
    u64 c4u = 0ull;
    const bool doFC = (p >= 2 && wave < 2);
    if (doFC) {
      const __bf16* h1r = h1buf + (par * NSTRIP * BB + (lane >> 1) * BB + w) * HS + (lane & 1) * 4;
      c4u = __hip_atomic_load((const u64*)h1r, __ATOMIC_RELAXED,
                              __HIP_MEMORY_SCOPE_AGENT);
    }

    // ---- per-wave poll: all 256 wave-flags >= p+2 (agent atomic loads) ----
    {
      const int f0 = lane * 4;
      int m;
      do {
        int a = __hip_atomic_load(&flags[(f0 + 0) * FSTR], __ATOMIC_RELAXED, __HIP_MEMORY_SCOPE_AGENT);
        int b = __hip_atomic_load(&flags[(f0 + 1) * FSTR], __ATOMIC_RELAXED, __HIP_MEMORY_SCOPE_AGENT);
        int c = __hip_atomic_load(&flags[(f0 + 2) * FSTR], __ATOMIC_RELAXED, __HIP_MEMORY_SCOPE_AGENT);
        int d = __hip_atomic_load(&flags[(f0 + 3) * FSTR], __ATOMIC_RELAXED, __HIP_MEMORY_SCOPE_AGENT);
        int ab = a < b ? a : b;
        int cd = c < d ? c : d;
        m = ab < cd ? ab : cd;
      } while (!__all(m >= p + 2));
    }

    // ---- FC reduce + store (data loaded pre-poll; RT hidden under spin) ----
    if (doFC) {
      const int t = p - 2;
      union { u64 u; __bf16 h[4]; } c4; c4.u = c4u;
      float s = (float)c4.h[0] * wfc0 + (float)c4.h[1] * wfc1
              + (float)c4.h[2] * wfc2 + (float)c4.h[3] * wfc3;
      #pragma unroll
      for (int off = 32; off > 0; off >>= 1) s += __shfl_down(s, off, 64);
      if (lane == 0) out[w * (TT * 2) + t * 2 + wave] = s + bfc[wave];
    }
  }
}

extern "C" void kernel_launch(void* const* d_in, const int* in_sizes, int n_in,
                              void* d_out, int out_size, void* d_ws, size_t ws_size,
                              hipStream_t stream) {
  u32* ws = (u32*)d_ws;
  init_ws<<<dim3(64), dim3(256), 0, stream>>>(ws);
  lstm2_persistent<<<dim3(768), dim3(256), 0, stream>>>(
      (const float*)d_in[0],  (const float*)d_in[1], (const float*)d_in[2],
      (const float*)d_in[3],  (const float*)d_in[4], (const float*)d_in[5],
      (const float*)d_in[6],  (const float*)d_in[7], (const float*)d_in[8],
      (const float*)d_in[9],  (const float*)d_in[10],
      (float*)d_out, ws);
}

// Round 9
// 5892.233 us; speedup vs baseline: 4.4009x; 4.4009x over previous
//
#include <hip/hip_runtime.h>

// 2-layer LSTM (B=64, T=2048, H=256), persistent kernel, SINGLE-XCD edition.
// R14 = R7 (verified 5927us) with THREE overlap deltas, sync mechanism
// UNTOUCHED (R13 proved per-wave flags + RMW stamps are toxic: 30MB HBM
// fetch from flag ping-pong; R7's plain-store stamp + wave0 agent poll is
// the verified-cheap configuration):
//  (1) FC h1 read split: agent load ISSUED after the stamp, CONSUMED after
//      the poll -> its ~900cy RT hides under the poll spin. (This split ran
//      correctly inside R13; only the sync mechanism there was bad.)
//  (2) A-frag waits counted: issue y, then a0[8], then a1[8]; wait vmcnt(8)
//      (y+a0 complete, m135 in-order retirement) before the L0 MFMA chain,
//      vmcnt(0) before L1 -> L0 compute overlaps a1 arrival. sched_barrier
//      after each wait (rule 18).
//  (3) Wfc/bfc hoisted to registers (removes 3 global reads from FC leg).
// Everything else byte-identical to R7: 64 WGs on one XCD (2/CU), 16 gate
// rows per WG per layer, h layout [par][32 strips][64 b][8 d] bf16, plain
// write-through h/flag stores, vmcnt(0) drain + barrier before stamp,
// wave0-only poll of 64 flags via agent atomic loads, 2 barriers/phase.

#define NWG 64      // participant workgroups
#define NSTRIP 32   // h strips (8 dims each)
#define BB 64
#define TT 2048
#define HH 256
#define HS 8        // dims per strip
#define HSW 4       // hidden dims per WG per layer
#define RS 16       // gate rows per WG per layer (4*HSW)

// workspace layout (dwords)
#define WS_H0    0        // 16384 dwords
#define WS_H1    16384    // 16384 dwords
#define WS_FLAGS 32768    // 64 flags, stride 16 dwords (1024 dwords)
#define WS_CNT   33792    // 16 dwords
#define WS_WIN   33808    // 1 dword
#define WS_NZERO 33808    // zeroed [0, WS_NZERO); winner set separately

typedef float  f32x4  __attribute__((ext_vector_type(4)));
typedef __bf16 bf16x8 __attribute__((ext_vector_type(8)));
typedef unsigned long long u64;
typedef unsigned int u32;

__device__ __forceinline__ float sigf(float x)   { return 1.0f / (1.0f + __expf(-x)); }
__device__ __forceinline__ float tanh_f(float x) { return 2.0f / (1.0f + __expf(-2.0f * x)) - 1.0f; }

__global__ void init_ws(u32* ws) {
  int i = blockIdx.x * blockDim.x + threadIdx.x;
  for (; i < WS_NZERO; i += gridDim.x * blockDim.x) ws[i] = 0u;
  if (blockIdx.x == 0 && threadIdx.x == 0) ((int*)ws)[WS_WIN] = -1;
}

__global__ __launch_bounds__(256, 2) void lstm2_persistent(
    const float* __restrict__ y,
    const float* __restrict__ Wih0, const float* __restrict__ Whh0,
    const float* __restrict__ bih0, const float* __restrict__ bhh0,
    const float* __restrict__ Wih1, const float* __restrict__ Whh1,
    const float* __restrict__ bih1, const float* __restrict__ bhh1,
    const float* __restrict__ Wfc,  const float* __restrict__ bfc,
    float* __restrict__ out,
    u32* __restrict__ ws)
{
  __bf16* h0buf = (__bf16*)(ws + WS_H0);   // [2][NSTRIP][BB][HS]
  __bf16* h1buf = (__bf16*)(ws + WS_H1);   // [2][NSTRIP][BB][HS]
  int*    flags = (int*)(ws + WS_FLAGS);   // stride 16 dwords per WG
  int*    cnt   = (int*)(ws + WS_CNT);
  int*    winner= (int*)(ws + WS_WIN);

  const int tid  = threadIdx.x;

  // ---- same-XCD election: first 64 WGs on one XCD participate, rest exit ----
  __shared__ int s_w;
  if (tid == 0) {
    // HW_REG_XCC_ID = 20, offset 0, size 32 -> imm = 20 | (31<<11)
    int xcc = __builtin_amdgcn_s_getreg(20 | (31 << 11)) & 0xF;
    int r = atomicAdd(&cnt[xcc], 1);               // device-scope (IC), one-time
    if (r == NWG - 1) atomicCAS(winner, -1, xcc);  // 64th registrant claims
    int wv;
    while ((wv = __hip_atomic_load(winner, __ATOMIC_RELAXED,
                                   __HIP_MEMORY_SCOPE_AGENT)) == -1) {}
    s_w = (wv == xcc && r < NWG) ? r : -1;
  }
  __syncthreads();
  const int w = s_w;
  if (w < 0) return;   // non-participant WG exits, frees its CU

  const int wave = tid >> 6;
  const int lane = tid & 63;
  const int ml   = lane & 15;   // row-within-tile for A, gate row for B
  const int kq   = lane >> 4;   // k-quad

  __shared__ float lds_g0[RS][BB + 4];
  __shared__ float lds_g1[RS][BB + 4];
  __shared__ float s_wih0[RS][4];
  __shared__ float s_b0[RS];
  __shared__ float s_b1[RS];

  // ---- load recurrent weights into per-wave VGPR B-fragments (bf16) ----
  // local gate row r = ml (0..15): gate = r>>2, dim-in-WG = r&3
  bf16x8 w0f[8];    // layer0: K=256
  bf16x8 w1f[16];   // layer1: K=512 = [Wih1 | Whh1]
  {
    const int r     = ml;
    const int rglob = (r >> 2) * 256 + w * HSW + (r & 3);
    #pragma unroll
    for (int s = 0; s < 8; s++) {
      const float* src = Whh0 + rglob * HH + s * 32 + kq * 8;
      bf16x8 f;
      #pragma unroll
      for (int j = 0; j < 8; j++) f[j] = (__bf16)src[j];
      w0f[s] = f;
    }
    #pragma unroll
    for (int s = 0; s < 16; s++) {
      const int k = s * 32 + kq * 8;
      const float* src = (k < 256) ? (Wih1 + rglob * HH + k)
                                   : (Whh1 + rglob * HH + (k - 256));
      bf16x8 f;
      #pragma unroll
      for (int j = 0; j < 8; j++) f[j] = (__bf16)src[j];
      w1f[s] = f;
    }
  }

  // ---- epilogue tables in LDS ----
  if (tid < RS) {
    const int r     = tid;
    const int rglob = (r >> 2) * 256 + w * HSW + (r & 3);
    s_b0[r] = bih0[rglob] + bhh0[rglob];
    s_b1[r] = bih1[rglob] + bhh1[rglob];
    #pragma unroll
    for (int j = 0; j < 4; j++) s_wih0[r][j] = Wih0[rglob * 4 + j];
  }
  __syncthreads();

  float c0 = 0.f, c1 = 0.f;

  const int b_epi = tid >> 2;          // epilogue batch (1 dim per thread)
  const int dl    = tid & 3;           // hidden dim within WG

  // ---- FC constants in registers (delta 3) ----
  float wfcr[4] = {0.f, 0.f, 0.f, 0.f};
  float bfcv = 0.f;
  if (wave < 2) {
    #pragma unroll
    for (int j = 0; j < 4; j++) wfcr[j] = Wfc[wave * HH + lane * 4 + j];
    bfcv = bfc[wave];
  }

  // sliding 4-tap input window: x[j] holds y[b_epi, p-3+j] (or -100 pad)
  float x[4] = {-100.0f, -100.0f, -100.0f, -100.0f};

  for (int p = 0; p < TT + 2; p++) {
    const int par  = p & 1;       // parity written by L0 this phase
    const int parm = par ^ 1;     // parity of h0(p-1) / h1(p-1)

    const bool doL0 = (p < TT);
    const bool doL1 = (p >= 1 && p <= TT);

    // ---- slide input window FIRST (y load oldest in vmcnt queue) ----
    x[0] = x[1]; x[1] = x[2]; x[2] = x[3];
    x[3] = (p < TT) ? y[b_epi * TT + p] : -100.0f;

    // ---- A-fragments: h0(p-1) and h1(p-2), L1-bypassing sc0 loads ----
    // (streaming one-shot loads: the PROVEN sc0 use; never spun on)
    bf16x8 a0[8], a1[8];
    {
      const int row = wave * 16 + ml;
      const __bf16* h0p = h0buf + (parm * NSTRIP * BB + kq * BB + row) * HS;
      const __bf16* h1p = h1buf + (par  * NSTRIP * BB + kq * BB + row) * HS;
      #pragma unroll
      for (int s = 0; s < 8; s++)
        asm volatile("global_load_dwordx4 %0, %1, off sc0"
                     : "=v"(a0[s]) : "v"(h0p + s * 4 * BB * HS) : "memory");
      #pragma unroll
      for (int s = 0; s < 8; s++)
        asm volatile("global_load_dwordx4 %0, %1, off sc0"
                     : "=v"(a1[s]) : "v"(h1p + s * 4 * BB * HS) : "memory");
    }

    // ---- counted wait: y + a0 complete (8 newest = a1 outstanding) ----
    asm volatile("s_waitcnt vmcnt(8)" ::: "memory");
    __builtin_amdgcn_sched_barrier(0);

    f32x4 acc0  = {0.f,0.f,0.f,0.f};
    f32x4 acc1a = {0.f,0.f,0.f,0.f};
    f32x4 acc1b = {0.f,0.f,0.f,0.f};

    if (doL0) {
      #pragma unroll
      for (int s = 0; s < 8; s++)
        acc0 = __builtin_amdgcn_mfma_f32_16x16x32_bf16(a0[s], w0f[s], acc0, 0, 0, 0);
    }
    if (doL1) {
      #pragma unroll
      for (int s = 0; s < 8; s++)
        acc1a = __builtin_amdgcn_mfma_f32_16x16x32_bf16(a0[s], w1f[s], acc1a, 0, 0, 0);
    }

    // ---- full wait: a1 complete, then L1's second half ----
    asm volatile("s_waitcnt vmcnt(0)" ::: "memory");
    __builtin_amdgcn_sched_barrier(0);

    if (doL1) {
      #pragma unroll
      for (int s = 0; s < 8; s++)
        acc1b = __builtin_amdgcn_mfma_f32_16x16x32_bf16(a1[s], w1f[s + 8], acc1b, 0, 0, 0);
    }

    // ---- spill gates to LDS (C layout: row=batch=kq*4+j, col=gate-row=ml) ----
    {
      const int bb = wave * 16 + kq * 4;
      if (doL0) {
        #pragma unroll
        for (int j = 0; j < 4; j++) lds_g0[ml][bb + j] = acc0[j];
      }
      if (doL1) {
        #pragma unroll
        for (int j = 0; j < 4; j++) lds_g1[ml][bb + j] = acc1a[j] + acc1b[j];
      }
    }
    __syncthreads();

    // ---- L0 epilogue: gates -> (c0,h0), publish h0(p) ----
    if (doL0) {
      const float gi = lds_g0[dl     ][b_epi] + s_b0[dl     ]
        + s_wih0[dl     ][0]*x[0] + s_wih0[dl     ][1]*x[1] + s_wih0[dl     ][2]*x[2] + s_wih0[dl     ][3]*x[3];
      const float gf = lds_g0[4 + dl ][b_epi] + s_b0[4 + dl ]
        + s_wih0[4 + dl ][0]*x[0] + s_wih0[4 + dl ][1]*x[1] + s_wih0[4 + dl ][2]*x[2] + s_wih0[4 + dl ][3]*x[3];
      const float gg = lds_g0[8 + dl ][b_epi] + s_b0[8 + dl ]
        + s_wih0[8 + dl ][0]*x[0] + s_wih0[8 + dl ][1]*x[1] + s_wih0[8 + dl ][2]*x[2] + s_wih0[8 + dl ][3]*x[3];
      const float go = lds_g0[12 + dl][b_epi] + s_b0[12 + dl]
        + s_wih0[12 + dl][0]*x[0] + s_wih0[12 + dl][1]*x[1] + s_wih0[12 + dl][2]*x[2] + s_wih0[12 + dl][3]*x[3];
      const float cn = sigf(gf) * c0 + sigf(gi) * tanh_f(gg);
      c0 = cn;
      const float hn = sigf(go) * tanh_f(cn);
      h0buf[(par * NSTRIP * BB + (w >> 1) * BB + b_epi) * HS + (w & 1) * 4 + dl] = (__bf16)hn;
    }

    // ---- L1 epilogue: publish h1(p-1) ----
    if (doL1) {
      const float gi = lds_g1[dl     ][b_epi] + s_b1[dl     ];
      const float gf = lds_g1[4 + dl ][b_epi] + s_b1[4 + dl ];
      const float gg = lds_g1[8 + dl ][b_epi] + s_b1[8 + dl ];
      const float go = lds_g1[12 + dl][b_epi] + s_b1[12 + dl];
      const float cn = sigf(gf) * c1 + sigf(gi) * tanh_f(gg);
      c1 = cn;
      const float hn = sigf(go) * tanh_f(cn);
      h1buf[(parm * NSTRIP * BB + (w >> 1) * BB + b_epi) * HS + (w & 1) * 4 + dl] = (__bf16)hn;
    }

    // ---- barrier publish: drain h stores to L2, then stamp flag ----
    asm volatile("s_waitcnt vmcnt(0)" ::: "memory");
    __syncthreads();
    if (tid == 0)
      __hip_atomic_store(&flags[w * 16], p + 2, __ATOMIC_RELAXED,
                         __HIP_MEMORY_SCOPE_WORKGROUP);   // plain store -> local L2

    // ---- FC load ISSUED now (agent path), consumed after the poll ----
    // (delta 1: the ~900cy agent RT hides under the poll spin)
    u64 c4u = 0ull;
    const bool doFC = (p >= 2 && wave < 2);
    if (doFC) {
      const __bf16* h1r = h1buf + (par * NSTRIP * BB + (lane >> 1) * BB + w) * HS + (lane & 1) * 4;
      c4u = __hip_atomic_load((const u64*)h1r, __ATOMIC_RELAXED,
                              __HIP_MEMORY_SCOPE_AGENT);
    }

    // ---- barrier wait: wave0 polls 64 flags, agent atomic loads (R7) ----
    if (tid < NWG) {
      while (__hip_atomic_load(&flags[tid * 16], __ATOMIC_RELAXED,
                               __HIP_MEMORY_SCOPE_AGENT) < p + 2) {}
    }

    // ---- FC consume + reduce + store (wave1 runs this during wave0 poll) ----
    if (doFC) {
      const int t = p - 2;
      union { u64 u; __bf16 h[4]; } c4; c4.u = c4u;
      float s = (float)c4.h[0] * wfcr[0] + (float)c4.h[1] * wfcr[1]
              + (float)c4.h[2] * wfcr[2] + (float)c4.h[3] * wfcr[3];
      #pragma unroll
      for (int off = 32; off > 0; off >>= 1) s += __shfl_down(s, off, 64);
      if (lane == 0) out[w * (TT * 2) + t * 2 + wave] = s + bfcv;
    }
    __syncthreads();
  }
}

extern "C" void kernel_launch(void* const* d_in, const int* in_sizes, int n_in,
                              void* d_out, int out_size, void* d_ws, size_t ws_size,
                              hipStream_t stream) {
  u32* ws = (u32*)d_ws;
  init_ws<<<dim3(64), dim3(256), 0, stream>>>(ws);
  lstm2_persistent<<<dim3(768), dim3(256), 0, stream>>>(
      (const float*)d_in[0],  (const float*)d_in[1], (const float*)d_in[2],
      (const float*)d_in[3],  (const float*)d_in[4], (const float*)d_in[5],
      (const float*)d_in[6],  (const float*)d_in[7], (const float*)d_in[8],
      (const float*)d_in[9],  (const float*)d_in[10],
      (float*)d_out, ws);
}